// Round 5
// baseline (360.067 us; speedup 1.0000x reference)
//
#include <hip/hip_runtime.h>
#include <cstdint>
#include <cstddef>

#define N_NODES 100000
#define E_EDGES 1000000
#define IN_DIM  128
#define HID     256
#define NG      64
#define EPSV    1e-5f
#define NBLK    391        // ceil(N/256)

typedef float f32x4 __attribute__((ext_vector_type(4)));
typedef __bf16 bf16x8 __attribute__((ext_vector_type(8)));
typedef unsigned short ushort8 __attribute__((ext_vector_type(8)));

// ---------------- ws layout (bytes) ----------------
// zeroed region [0, ZERO_BYTES)
static constexpr size_t OFF_DEG    = 0;          // N int (aliased by Wt after k_scan3)
static constexpr size_t OFF_CSUM   = 400000;     // 256 f32
static constexpr size_t OFF_CSQ    = 401024;     // 256 f32
static constexpr size_t OFF_POOLR  = 402048;     // 64*256 f32
static constexpr size_t OFF_CSUM1  = 467584;
static constexpr size_t OFF_CSQ1   = 468608;
static constexpr size_t OFF_CSUM2  = 469632;
static constexpr size_t OFF_CSQ2   = 470656;
static constexpr size_t ZERO_BYTES = 471680;
// non-zeroed
static constexpr size_t OFF_BSUM   = 471680;     // NBLK int (1564 B)
static constexpr size_t OFF_START  = 473344;     // 65 int
static constexpr size_t OFF_ROWOFF = 473728;     // (N+1) int
static constexpr size_t OFF_CURSOR = 873856;     // N int -- dead after k_scatter; aliased:
static constexpr size_t OFF_POOLF  = 873856;     //   64*256 f32
static constexpr size_t OFF_Y1R    = 939392;     //   64*256 f32
static constexpr size_t OFF_PBUF   = 1004928;    //   64*256 f32
static constexpr size_t OFF_Y2R    = 1070464;    //   64*256 f32
static constexpr size_t OFF_SSRC   = 1273856;    // E int
static constexpr size_t OFF_FB16   = 5273856;    // N*128 bf16
static constexpr size_t OFF_HN16   = 30873856;   // N*128 bf16 (end 56,473,856)
static constexpr size_t OFF_WT     = 0;          // 256*256 bf16, aliases deg (dead after scan3)

__device__ __forceinline__ unsigned short f2bf(float f) {
    union { float f; unsigned u; } x; x.f = f;
    unsigned r = x.u + 0x7FFFu + ((x.u >> 16) & 1u);
    return (unsigned short)(r >> 16);
}
__device__ __forceinline__ float bf2f(unsigned short h) {
    union { unsigned u; float f; } x; x.u = ((unsigned)h) << 16;
    return x.f;
}

// -------- fused: feat->bf16 cvt + degree count + graph bounds --------
__global__ __launch_bounds__(256) void k_prep(const float* __restrict__ feat,
                                              const int* __restrict__ dst,
                                              const int* __restrict__ gid,
                                              unsigned short* __restrict__ fb,
                                              int* __restrict__ deg,
                                              int* __restrict__ start) {
    int g = blockIdx.x * blockDim.x + threadIdx.x;
    int stride = gridDim.x * blockDim.x;
    // cvt: 1.6M chunks of 8 floats
    const float4* f4 = (const float4*)feat;
    for (int i = g; i < (N_NODES * IN_DIM / 8); i += stride) {
        float4 a = f4[i * 2], b = f4[i * 2 + 1];
        ushort8 v;
        v[0] = f2bf(a.x); v[1] = f2bf(a.y); v[2] = f2bf(a.z); v[3] = f2bf(a.w);
        v[4] = f2bf(b.x); v[5] = f2bf(b.y); v[6] = f2bf(b.z); v[7] = f2bf(b.w);
        *(ushort8*)&fb[(size_t)i * 8] = v;
    }
    // degree count
    for (int e = g; e < E_EDGES; e += stride) atomicAdd(&deg[dst[e]], 1);
    // graph segment boundaries (gid sorted)
    for (int n = g; n < N_NODES; n += stride) {
        int b = gid[n];
        if (n == 0) {
            for (int q = 0; q <= b; ++q) start[q] = 0;
        } else {
            int a = gid[n - 1];
            for (int q = a + 1; q <= b; ++q) start[q] = n;
        }
        if (n == N_NODES - 1) {
            for (int q = b + 1; q <= NG; ++q) start[q] = N_NODES;
        }
    }
}

// -------- hierarchical scan: block sums --------
__global__ __launch_bounds__(256) void k_scan1(const int* __restrict__ deg, int* __restrict__ bsum) {
    __shared__ int sh[256];
    int b = blockIdx.x, t = threadIdx.x;
    int n = b * 256 + t;
    sh[t] = (n < N_NODES) ? deg[n] : 0;
    __syncthreads();
    for (int s = 128; s > 0; s >>= 1) {
        if (t < s) sh[t] += sh[t + s];
        __syncthreads();
    }
    if (t == 0) bsum[b] = sh[0];
}

// -------- scan of block sums (exclusive, in place) --------
__global__ __launch_bounds__(512) void k_scan2(int* __restrict__ bsum, int* __restrict__ row_off) {
    __shared__ int sh[512];
    int t = threadIdx.x;
    int v = (t < NBLK) ? bsum[t] : 0;
    sh[t] = v;
    __syncthreads();
    for (int off = 1; off < 512; off <<= 1) {
        int add = (t >= off) ? sh[t - off] : 0;
        __syncthreads();
        sh[t] += add;
        __syncthreads();
    }
    if (t < NBLK) bsum[t] = sh[t] - v;  // exclusive block offset
    if (t == 0) row_off[N_NODES] = E_EDGES;
}

// -------- per-block exclusive scan + offset --------
__global__ __launch_bounds__(256) void k_scan3(const int* __restrict__ deg, const int* __restrict__ bsum,
                                               int* __restrict__ row_off, int* __restrict__ cursor) {
    __shared__ int sh[256];
    int b = blockIdx.x, t = threadIdx.x;
    int n = b * 256 + t;
    int v = (n < N_NODES) ? deg[n] : 0;
    sh[t] = v;
    __syncthreads();
    for (int off = 1; off < 256; off <<= 1) {
        int add = (t >= off) ? sh[t - off] : 0;
        __syncthreads();
        sh[t] += add;
        __syncthreads();
    }
    int ex = bsum[b] + sh[t] - v;
    if (n < N_NODES) { row_off[n] = ex; cursor[n] = ex; }
}

// -------- weight prepack: Wt[n][k] bf16 (aliases dead deg region) --------
__global__ __launch_bounds__(256) void k_prepw(const float* __restrict__ W_self,
                                               const float* __restrict__ W_neigh,
                                               unsigned short* __restrict__ Wt) {
    int n = blockIdx.x, k = threadIdx.x;
    float w = (k < 128) ? W_self[k * HID + n] : W_neigh[(k - 128) * HID + n];
    Wt[n * 256 + k] = f2bf(w);
}

// -------- scatter edges into CSR order: 4 edges/thread, batched MLP --------
__global__ __launch_bounds__(256) void k_scatter(const int4* __restrict__ src4,
                                                 const int4* __restrict__ dst4,
                                                 int* __restrict__ cursor,
                                                 int* __restrict__ sorted_src) {
    int i = blockIdx.x * blockDim.x + threadIdx.x;
    if (i >= E_EDGES / 4) return;
    int4 s = src4[i];
    int4 d = dst4[i];
    // 4 independent atomics in flight, then 4 independent stores
    int p0 = atomicAdd(&cursor[d.x], 1);
    int p1 = atomicAdd(&cursor[d.y], 1);
    int p2 = atomicAdd(&cursor[d.z], 1);
    int p3 = atomicAdd(&cursor[d.w], 1);
    sorted_src[p0] = s.x;
    sorted_src[p1] = s.y;
    sorted_src[p2] = s.z;
    sorted_src[p3] = s.w;
}

// -------- mean aggregation (bf16 gather, bf16 out): one wave per node --------
__global__ __launch_bounds__(256) void k_agg(const unsigned short* __restrict__ fb,
                                             const int* __restrict__ row_off,
                                             const int* __restrict__ sorted_src,
                                             unsigned short* __restrict__ hb) {
    int wave = threadIdx.x >> 6;
    int lane = threadIdx.x & 63;
    int n = blockIdx.x * 4 + wave;
    if (n >= N_NODES) return;
    int k0 = __builtin_amdgcn_readfirstlane(row_off[n]);
    int k1 = __builtin_amdgcn_readfirstlane(row_off[n + 1]);
    float ax = 0.f, ay = 0.f;
    int k = k0;
    for (; k + 8 <= k1; k += 8) {
        int s[8];
#pragma unroll
        for (int q = 0; q < 8; ++q) s[q] = sorted_src[k + q];
        unsigned u[8];
#pragma unroll
        for (int q = 0; q < 8; ++q) u[q] = *(const unsigned*)&fb[(size_t)s[q] * IN_DIM + lane * 2];
#pragma unroll
        for (int q = 0; q < 8; ++q) { ax += bf2f(u[q] & 0xffff); ay += bf2f(u[q] >> 16); }
    }
    if (k + 4 <= k1) {
        int s[4];
#pragma unroll
        for (int q = 0; q < 4; ++q) s[q] = sorted_src[k + q];
        unsigned u[4];
#pragma unroll
        for (int q = 0; q < 4; ++q) u[q] = *(const unsigned*)&fb[(size_t)s[q] * IN_DIM + lane * 2];
#pragma unroll
        for (int q = 0; q < 4; ++q) { ax += bf2f(u[q] & 0xffff); ay += bf2f(u[q] >> 16); }
        k += 4;
    }
    for (; k < k1; ++k) {
        unsigned u0 = *(const unsigned*)&fb[(size_t)sorted_src[k] * IN_DIM + lane * 2];
        ax += bf2f(u0 & 0xffff);
        ay += bf2f(u0 >> 16);
    }
    float inv = 1.f / fmaxf((float)(k1 - k0), 1.f);
    unsigned out = (unsigned)f2bf(ax * inv) | ((unsigned)f2bf(ay * inv) << 16);
    *(unsigned*)&hb[(size_t)n * IN_DIM + lane * 2] = out;
}

// -------- MFMA conv GEMM + relu + BN stats + graph pooling --------
// 1024 threads / 16 waves; wave w owns output cols [w*16, w*16+16), B held in VGPRs.
// Block processes 256 contiguous rows as 4 tiles of 64.
__global__ __launch_bounds__(1024, 4) void k_gemm(const unsigned short* __restrict__ fb,
                                                  const unsigned short* __restrict__ hb,
                                                  const unsigned short* __restrict__ Wt,
                                                  const float* __restrict__ b_conv,
                                                  const int* __restrict__ gid,
                                                  float* __restrict__ colsum,
                                                  float* __restrict__ colsq,
                                                  float* __restrict__ pooled_raw) {
    __shared__ unsigned short A_l[64 * 264];   // 64 rows x 256 k, stride 264 (pad 8)
    __shared__ float pool_l[8][256];
    __shared__ float csum_l[256], csq_l[256];
    __shared__ int gid_s[256];

    int tid = threadIdx.x;
    int lane = tid & 63;
    int wid = tid >> 6;            // 0..15
    int lr15 = lane & 15;
    int lq = lane >> 4;            // 0..3
    int ncol = wid * 16 + lr15;    // this lane's output column
    int n0 = blockIdx.x * 256;

    if (tid < 256) {
        csum_l[tid] = 0.f; csq_l[tid] = 0.f;
        gid_s[tid] = (n0 + tid < N_NODES) ? gid[n0 + tid] : 0x7fffffff;
    }
    ((float*)pool_l)[tid] = 0.f;
    ((float*)pool_l)[1024 + tid] = 0.f;

    // B fragments in registers: 8 k-steps x bf16x8
    bf16x8 bfr[8];
#pragma unroll
    for (int kc = 0; kc < 8; ++kc)
        bfr[kc] = *(const bf16x8*)&Wt[(size_t)ncol * 256 + kc * 32 + lq * 8];
    float bc = b_conv[ncol];
    int g_base = gid[n0];

    float cs = 0.f, cq = 0.f;

    for (int t = 0; t < 4; ++t) {
        int bn0 = n0 + t * 64;
        __syncthreads();   // init done / previous tile's A reads done
        // stage A tile: 64 rows x 256 k (2048 x 16B chunks, 2 per thread)
#pragma unroll
        for (int i = 0; i < 2; ++i) {
            int idx = i * 1024 + tid;
            int r = idx >> 5;          // 0..63
            int c = idx & 31;          // 16B chunk within row (k = c*8)
            int node = bn0 + r;
            ushort8 v = {0, 0, 0, 0, 0, 0, 0, 0};
            if (node < N_NODES) {
                v = (c < 16) ? *(const ushort8*)&fb[(size_t)node * IN_DIM + c * 8]
                             : *(const ushort8*)&hb[(size_t)node * IN_DIM + (c - 16) * 8];
            }
            *(ushort8*)&A_l[r * 264 + c * 8] = v;
        }
        __syncthreads();

        f32x4 acc[4];
#pragma unroll
        for (int rf = 0; rf < 4; ++rf) acc[rf] = (f32x4)0.f;
#pragma unroll
        for (int kc = 0; kc < 8; ++kc) {
#pragma unroll
            for (int rf = 0; rf < 4; ++rf) {
                bf16x8 a = *(const bf16x8*)&A_l[(rf * 16 + lr15) * 264 + kc * 32 + lq * 8];
                acc[rf] = __builtin_amdgcn_mfma_f32_16x16x32_bf16(a, bfr[kc], acc[rf], 0, 0, 0);
            }
        }

        // epilogue: bias, relu, stats (regs), pooling (run-length -> LDS slots)
        float ps = 0.f;
        int cg = -1;
#pragma unroll
        for (int rf = 0; rf < 4; ++rf) {
#pragma unroll
            for (int j = 0; j < 4; ++j) {
                int lr = rf * 16 + lq * 4 + j;
                int node = bn0 + lr;
                if (node < N_NODES) {
                    int g = gid_s[t * 64 + lr];
                    if (g != cg) {
                        if (cg >= 0 && ps != 0.f) {
                            int slot = cg - g_base;
                            if (slot < 8) atomicAdd(&pool_l[slot][ncol], ps);
                            else          atomicAdd(&pooled_raw[cg * HID + ncol], ps);
                        }
                        ps = 0.f; cg = g;
                    }
                    float v = fmaxf(acc[rf][j] + bc, 0.f);
                    cs += v; cq += v * v; ps += v;
                }
            }
        }
        if (cg >= 0 && ps != 0.f) {
            int slot = cg - g_base;
            if (slot < 8) atomicAdd(&pool_l[slot][ncol], ps);
            else          atomicAdd(&pooled_raw[cg * HID + ncol], ps);
        }
    }

    // block-level reductions -> global
    atomicAdd(&csum_l[ncol], cs);
    atomicAdd(&csq_l[ncol], cq);
    __syncthreads();
    if (tid < 256) {
        atomicAdd(&colsum[tid], csum_l[tid]);
        atomicAdd(&colsq[tid], csq_l[tid]);
    }
#pragma unroll
    for (int i = 0; i < 2; ++i) {
        int idx = i * 1024 + tid;
        int slot = idx >> 8, c = idx & 255;
        int gg = g_base + slot;
        float v = pool_l[slot][c];
        if (gg < NG && v != 0.f) atomicAdd(&pooled_raw[gg * HID + c], v);
    }
}

// -------- finalize conv BN (affine on pooled sums) --------
__global__ void k_head_prep(const float* __restrict__ colsum, const float* __restrict__ colsq,
                            const float* __restrict__ gamma, const float* __restrict__ beta,
                            const int* __restrict__ start, const float* __restrict__ pooled_raw,
                            float* __restrict__ pooled_final) {
    int c = threadIdx.x;
    float mu = colsum[c] * (1.0f / N_NODES);
    float var = colsq[c] * (1.0f / N_NODES) - mu * mu;
    float a = gamma[c] * rsqrtf(var + EPSV);
    float off = beta[c] - a * mu;
    for (int g = 0; g < NG; ++g) {
        float cg = (float)(start[g + 1] - start[g]);
        pooled_final[g * HID + c] = a * pooled_raw[g * HID + c] + cg * off;
    }
}

// -------- lp linear: y = relu(x@W + b), accumulate BN stats --------
__global__ __launch_bounds__(256) void k_lp(const float* __restrict__ x,
                                            const float* __restrict__ W,
                                            const float* __restrict__ b,
                                            float* __restrict__ yrelu,
                                            float* __restrict__ csum,
                                            float* __restrict__ csq) {
    __shared__ float xl[256];
    int g = blockIdx.x, c = threadIdx.x;
    xl[c] = x[g * HID + c];
    __syncthreads();
    float acc = b[c];
#pragma unroll 8
    for (int k = 0; k < HID; ++k) acc = fmaf(xl[k], W[k * HID + c], acc);
    float r = fmaxf(acc, 0.f);
    yrelu[g * HID + c] = r;
    atomicAdd(&csum[c], r);
    atomicAdd(&csq[c], r * r);
}

// -------- apply BN (write p to ws and d_out) --------
__global__ void k_bn(const float* __restrict__ yrelu, const float* __restrict__ csum,
                     const float* __restrict__ csq, const float* __restrict__ gamma,
                     const float* __restrict__ beta, float* __restrict__ out_a,
                     float* __restrict__ out_b) {
    int g = blockIdx.x, c = threadIdx.x;
    float mu = csum[c] * (1.f / NG);
    float var = csq[c] * (1.f / NG) - mu * mu;
    float a = gamma[c] * rsqrtf(var + EPSV);
    float v = (yrelu[g * HID + c] - mu) * a + beta[c];
    out_a[g * HID + c] = v;
    out_b[g * HID + c] = v;
}

// -------- apply BN + log_softmax --------
__global__ __launch_bounds__(256) void k_bnsm(const float* __restrict__ yrelu,
                                              const float* __restrict__ csum,
                                              const float* __restrict__ csq,
                                              const float* __restrict__ gamma,
                                              const float* __restrict__ beta,
                                              float* __restrict__ out) {
    __shared__ float red[256];
    int g = blockIdx.x, c = threadIdx.x;
    float mu = csum[c] * (1.f / NG);
    float var = csq[c] * (1.f / NG) - mu * mu;
    float a = gamma[c] * rsqrtf(var + EPSV);
    float z = (yrelu[g * HID + c] - mu) * a + beta[c];
    red[c] = z;
    __syncthreads();
    for (int s = 128; s > 0; s >>= 1) {
        if (c < s) red[c] = fmaxf(red[c], red[c + s]);
        __syncthreads();
    }
    float m = red[0];
    __syncthreads();
    red[c] = expf(z - m);
    __syncthreads();
    for (int s = 128; s > 0; s >>= 1) {
        if (c < s) red[c] += red[c + s];
        __syncthreads();
    }
    float lse = m + logf(red[0]);
    out[g * HID + c] = z - lse;
}

extern "C" void kernel_launch(void* const* d_in, const int* in_sizes, int n_in,
                              void* d_out, int out_size, void* d_ws, size_t ws_size,
                              hipStream_t stream) {
    const float* feat    = (const float*)d_in[0];
    const float* W_self  = (const float*)d_in[1];
    const float* W_neigh = (const float*)d_in[2];
    const float* b_conv  = (const float*)d_in[3];
    const float* g_conv  = (const float*)d_in[4];
    const float* be_conv = (const float*)d_in[5];
    const float* W_lp    = (const float*)d_in[6];
    const float* b_lp    = (const float*)d_in[7];
    const float* g_lp    = (const float*)d_in[8];
    const float* be_lp   = (const float*)d_in[9];
    const int* src = (const int*)d_in[10];
    const int* dst = (const int*)d_in[11];
    const int* gid = (const int*)d_in[12];

    char* ws = (char*)d_ws;
    int*   deg        = (int*)(ws + OFF_DEG);
    unsigned short* Wt = (unsigned short*)(ws + OFF_WT);   // aliases deg (dead after scan3)
    float* colsum     = (float*)(ws + OFF_CSUM);
    float* colsq      = (float*)(ws + OFF_CSQ);
    float* pooled_raw = (float*)(ws + OFF_POOLR);
    float* csum1      = (float*)(ws + OFF_CSUM1);
    float* csq1       = (float*)(ws + OFF_CSQ1);
    float* csum2      = (float*)(ws + OFF_CSUM2);
    float* csq2       = (float*)(ws + OFF_CSQ2);
    int*   bsum       = (int*)(ws + OFF_BSUM);
    int*   start      = (int*)(ws + OFF_START);
    int*   row_off    = (int*)(ws + OFF_ROWOFF);
    int*   cursor     = (int*)(ws + OFF_CURSOR);
    float* pooled_f   = (float*)(ws + OFF_POOLF);
    float* y1r        = (float*)(ws + OFF_Y1R);
    float* p_buf      = (float*)(ws + OFF_PBUF);
    float* y2r        = (float*)(ws + OFF_Y2R);
    int*   sorted_src = (int*)(ws + OFF_SSRC);
    unsigned short* fb = (unsigned short*)(ws + OFF_FB16);
    unsigned short* hb = (unsigned short*)(ws + OFF_HN16);

    float* out_ls = (float*)d_out;             // [64,256] log_softmax
    float* out_p  = out_ls + NG * HID;         // [64,256] p

    hipMemsetAsync(d_ws, 0, ZERO_BYTES, stream);
    k_prep<<<2048, 256, 0, stream>>>(feat, dst, gid, fb, deg, start);
    k_scan1<<<NBLK, 256, 0, stream>>>(deg, bsum);
    k_scan2<<<1, 512, 0, stream>>>(bsum, row_off);
    k_scan3<<<NBLK, 256, 0, stream>>>(deg, bsum, row_off, cursor);
    k_prepw<<<256, 256, 0, stream>>>(W_self, W_neigh, Wt);   // deg region now dead
    k_scatter<<<(E_EDGES / 4 + 255) / 256, 256, 0, stream>>>((const int4*)src, (const int4*)dst,
                                                             cursor, sorted_src);
    k_agg<<<25000, 256, 0, stream>>>(fb, row_off, sorted_src, hb);
    k_gemm<<<NBLK, 1024, 0, stream>>>(fb, hb, Wt, b_conv, gid, colsum, colsq, pooled_raw);
    k_head_prep<<<1, 256, 0, stream>>>(colsum, colsq, g_conv, be_conv, start,
                                       pooled_raw, pooled_f);
    k_lp<<<NG, 256, 0, stream>>>(pooled_f, W_lp, b_lp, y1r, csum1, csq1);
    k_bn<<<NG, 256, 0, stream>>>(y1r, csum1, csq1, g_lp, be_lp, p_buf, out_p);
    k_lp<<<NG, 256, 0, stream>>>(p_buf, W_lp, b_lp, y2r, csum2, csq2);
    k_bnsm<<<NG, 256, 0, stream>>>(y2r, csum2, csq2, g_lp, be_lp, out_ls);
}

// Round 6
// 305.143 us; speedup vs baseline: 1.1800x; 1.1800x over previous
//
#include <hip/hip_runtime.h>
#include <cstdint>
#include <cstddef>

#define N_NODES 100000
#define E_EDGES 1000000
#define IN_DIM  128
#define HID     256
#define NG      64
#define EPSV    1e-5f
#define NBLK    391        // ceil(N/256) = #buckets (bucket = dst>>8)
#define HBLK    64         // histogram/bucket blocks
#define EPB     15625      // edges per hist/bucket block (64*15625 = 1M)

typedef float f32x4 __attribute__((ext_vector_type(4)));
typedef __bf16 bf16x8 __attribute__((ext_vector_type(8)));
typedef unsigned short ushort8 __attribute__((ext_vector_type(8)));

// ---------------- ws layout (bytes) ----------------
static constexpr size_t OFF_WT     = 0;          // 256*256 bf16 = 131072
static constexpr size_t OFF_START  = 131072;     // 65 int
// zeroed region
static constexpr size_t ZERO_START = 131584;
static constexpr size_t OFF_CSUM   = 131584;     // 256 f32
static constexpr size_t OFF_CSQ    = 132608;     // 256 f32
static constexpr size_t OFF_POOLR  = 133632;     // 64*256 f32 -> 199168
static constexpr size_t OFF_CSUM1  = 199168;
static constexpr size_t OFF_CSQ1   = 200192;
static constexpr size_t OFF_CSUM2  = 201216;
static constexpr size_t OFF_CSQ2   = 202240;
static constexpr size_t ZERO_END   = 203264;
// non-zeroed
static constexpr size_t OFF_BBASE  = 203264;     // 392 int
static constexpr size_t OFF_HISTM  = 204832;     // 64*391 int
static constexpr size_t OFF_BASES  = 304928;     // 64*391 int
static constexpr size_t OFF_ROWOFF = 405024;     // (N+1) int -> 805028
static constexpr size_t OFF_Y1R    = 805056;     // 64*256 f32
static constexpr size_t OFF_PBUF   = 870592;     // 64*256 f32
static constexpr size_t OFF_Y2R    = 936128;     // 64*256 f32
static constexpr size_t OFF_SSRC   = 1001664;    // E int -> 5001664
static constexpr size_t OFF_FB16   = 5001664;    // N*128 bf16 -> 30601664
static constexpr size_t OFF_HN16   = 30601664;   // N*128 bf16 -> 56201664
// bucketed staging aliases HN16 (dead until k_agg writes hb)
static constexpr size_t OFF_BSRC   = 30601664;   // E int -> 34601664
static constexpr size_t OFF_BDLO   = 34601664;   // E u8  -> 35601664

__device__ __forceinline__ unsigned short f2bf(float f) {
    union { float f; unsigned u; } x; x.f = f;
    unsigned r = x.u + 0x7FFFu + ((x.u >> 16) & 1u);
    return (unsigned short)(r >> 16);
}
__device__ __forceinline__ float bf2f(unsigned short h) {
    union { unsigned u; float f; } x; x.u = ((unsigned)h) << 16;
    return x.f;
}

// -------- fused: feat->bf16 cvt + graph bounds + weight prepack --------
__global__ __launch_bounds__(256) void k_prep(const float* __restrict__ feat,
                                              const int* __restrict__ gid,
                                              const float* __restrict__ W_self,
                                              const float* __restrict__ W_neigh,
                                              unsigned short* __restrict__ fb,
                                              int* __restrict__ start,
                                              unsigned short* __restrict__ Wt) {
    int g = blockIdx.x * blockDim.x + threadIdx.x;
    int stride = gridDim.x * blockDim.x;
    const float4* f4 = (const float4*)feat;
    for (int i = g; i < (N_NODES * IN_DIM / 8); i += stride) {
        float4 a = f4[i * 2], b = f4[i * 2 + 1];
        ushort8 v;
        v[0] = f2bf(a.x); v[1] = f2bf(a.y); v[2] = f2bf(a.z); v[3] = f2bf(a.w);
        v[4] = f2bf(b.x); v[5] = f2bf(b.y); v[6] = f2bf(b.z); v[7] = f2bf(b.w);
        *(ushort8*)&fb[(size_t)i * 8] = v;
    }
    // weight prepack Wt[n][k]
    for (int i = g; i < HID * HID; i += stride) {
        int n = i >> 8, k = i & 255;
        float w = (k < 128) ? W_self[k * HID + n] : W_neigh[(k - 128) * HID + n];
        Wt[i] = f2bf(w);
    }
    // graph segment boundaries (gid sorted)
    for (int n = g; n < N_NODES; n += stride) {
        int b = gid[n];
        if (n == 0) {
            for (int q = 0; q <= b; ++q) start[q] = 0;
        } else {
            int a = gid[n - 1];
            for (int q = a + 1; q <= b; ++q) start[q] = n;
        }
        if (n == N_NODES - 1) {
            for (int q = b + 1; q <= NG; ++q) start[q] = N_NODES;
        }
    }
}

// -------- pass 1: per-block coarse histogram (LDS only, no global atomics) --------
__global__ __launch_bounds__(1024) void k_hist(const int* __restrict__ dst,
                                               int* __restrict__ histm) {
    __shared__ int h[NBLK];
    int blk = blockIdx.x, t = threadIdx.x;
    for (int i = t; i < NBLK; i += 1024) h[i] = 0;
    __syncthreads();
    int e0 = blk * EPB, e1 = e0 + EPB;
    for (int e = e0 + t; e < e1; e += 1024) atomicAdd(&h[dst[e] >> 8], 1);
    __syncthreads();
    for (int i = t; i < NBLK; i += 1024) histm[blk * NBLK + i] = h[i];
}

// -------- pass 2: bucket totals, exclusive scan, per-block bases --------
__global__ __launch_bounds__(512) void k_bscan(const int* __restrict__ histm,
                                               int* __restrict__ bbase,
                                               int* __restrict__ bases) {
    __shared__ int tot[512];
    int t = threadIdx.x;
    int s = 0;
    if (t < NBLK)
        for (int blk = 0; blk < HBLK; ++blk) s += histm[blk * NBLK + t];
    tot[t] = (t < NBLK) ? s : 0;
    __syncthreads();
    for (int off = 1; off < 512; off <<= 1) {
        int add = (t >= off) ? tot[t - off] : 0;
        __syncthreads();
        tot[t] += add;
        __syncthreads();
    }
    if (t < NBLK) {
        int excl = tot[t] - s;      // exclusive prefix (tot is inclusive)
        bbase[t] = excl;
        int run = excl;
        for (int blk = 0; blk < HBLK; ++blk) {
            bases[blk * NBLK + t] = run;
            run += histm[blk * NBLK + t];
        }
    }
    if (t == 0) bbase[NBLK] = E_EDGES;
}

// -------- pass 3: bucketed scatter (LDS cursors, grouped writes) --------
__global__ __launch_bounds__(1024) void k_bucket(const int* __restrict__ src,
                                                 const int* __restrict__ dst,
                                                 const int* __restrict__ bases,
                                                 int* __restrict__ bsrc,
                                                 unsigned char* __restrict__ bdlo) {
    __shared__ int cur[NBLK];
    int blk = blockIdx.x, t = threadIdx.x;
    for (int i = t; i < NBLK; i += 1024) cur[i] = bases[blk * NBLK + i];
    __syncthreads();
    int e0 = blk * EPB, e1 = e0 + EPB;
    for (int e = e0 + t; e < e1; e += 1024) {
        int d = dst[e];
        int pos = atomicAdd(&cur[d >> 8], 1);
        bsrc[pos] = src[e];
        bdlo[pos] = (unsigned char)(d & 255);
    }
}

// -------- pass 4: per-bucket local counting sort -> sorted_src + row_off --------
__global__ __launch_bounds__(256) void k_lsort(const int* __restrict__ bbase,
                                               const int* __restrict__ bsrc,
                                               const unsigned char* __restrict__ bdlo,
                                               int* __restrict__ sorted_src,
                                               int* __restrict__ row_off) {
    __shared__ int h[256];
    __shared__ int cur[256];
    int b = blockIdx.x, t = threadIdx.x;
    int base = bbase[b], end = bbase[b + 1];
    h[t] = 0;
    __syncthreads();
    for (int e = base + t; e < end; e += 256) atomicAdd(&h[bdlo[e]], 1);
    __syncthreads();
    int v = h[t];
    for (int off = 1; off < 256; off <<= 1) {
        int add = (t >= off) ? h[t - off] : 0;
        __syncthreads();
        h[t] += add;
        __syncthreads();
    }
    int excl = h[t] - v;
    int node = b * 256 + t;
    if (node < N_NODES) row_off[node] = base + excl;
    cur[t] = excl;
    __syncthreads();
    for (int e = base + t; e < end; e += 256) {
        int d = bdlo[e];
        int pos = base + atomicAdd(&cur[d], 1);
        sorted_src[pos] = bsrc[e];
    }
    if (b == 0 && t == 0) row_off[N_NODES] = E_EDGES;
}

// -------- mean aggregation (bf16 gather, bf16 out): one wave per node --------
__global__ __launch_bounds__(256) void k_agg(const unsigned short* __restrict__ fb,
                                             const int* __restrict__ row_off,
                                             const int* __restrict__ sorted_src,
                                             unsigned short* __restrict__ hb) {
    int wave = threadIdx.x >> 6;
    int lane = threadIdx.x & 63;
    int n = blockIdx.x * 4 + wave;
    if (n >= N_NODES) return;
    int k0 = __builtin_amdgcn_readfirstlane(row_off[n]);
    int k1 = __builtin_amdgcn_readfirstlane(row_off[n + 1]);
    float ax = 0.f, ay = 0.f;
    int k = k0;
    for (; k + 8 <= k1; k += 8) {
        int s[8];
#pragma unroll
        for (int q = 0; q < 8; ++q) s[q] = sorted_src[k + q];
        unsigned u[8];
#pragma unroll
        for (int q = 0; q < 8; ++q) u[q] = *(const unsigned*)&fb[(size_t)s[q] * IN_DIM + lane * 2];
#pragma unroll
        for (int q = 0; q < 8; ++q) { ax += bf2f(u[q] & 0xffff); ay += bf2f(u[q] >> 16); }
    }
    if (k + 4 <= k1) {
        int s[4];
#pragma unroll
        for (int q = 0; q < 4; ++q) s[q] = sorted_src[k + q];
        unsigned u[4];
#pragma unroll
        for (int q = 0; q < 4; ++q) u[q] = *(const unsigned*)&fb[(size_t)s[q] * IN_DIM + lane * 2];
#pragma unroll
        for (int q = 0; q < 4; ++q) { ax += bf2f(u[q] & 0xffff); ay += bf2f(u[q] >> 16); }
        k += 4;
    }
    for (; k < k1; ++k) {
        unsigned u0 = *(const unsigned*)&fb[(size_t)sorted_src[k] * IN_DIM + lane * 2];
        ax += bf2f(u0 & 0xffff);
        ay += bf2f(u0 >> 16);
    }
    float inv = 1.f / fmaxf((float)(k1 - k0), 1.f);
    unsigned out = (unsigned)f2bf(ax * inv) | ((unsigned)f2bf(ay * inv) << 16);
    *(unsigned*)&hb[(size_t)n * IN_DIM + lane * 2] = out;
}

// -------- MFMA conv GEMM + relu + BN stats + graph pooling --------
__global__ __launch_bounds__(1024, 4) void k_gemm(const unsigned short* __restrict__ fb,
                                                  const unsigned short* __restrict__ hb,
                                                  const unsigned short* __restrict__ Wt,
                                                  const float* __restrict__ b_conv,
                                                  const int* __restrict__ gid,
                                                  float* __restrict__ colsum,
                                                  float* __restrict__ colsq,
                                                  float* __restrict__ pooled_raw) {
    __shared__ unsigned short A_l[64 * 264];   // 64 rows x 256 k, stride 264 (pad 8)
    __shared__ float pool_l[8][256];
    __shared__ float csum_l[256], csq_l[256];
    __shared__ int gid_s[256];

    int tid = threadIdx.x;
    int lane = tid & 63;
    int wid = tid >> 6;            // 0..15
    int lr15 = lane & 15;
    int lq = lane >> 4;            // 0..3
    int ncol = wid * 16 + lr15;
    int n0 = blockIdx.x * 256;

    if (tid < 256) {
        csum_l[tid] = 0.f; csq_l[tid] = 0.f;
        gid_s[tid] = (n0 + tid < N_NODES) ? gid[n0 + tid] : 0x7fffffff;
    }
    ((float*)pool_l)[tid] = 0.f;
    ((float*)pool_l)[1024 + tid] = 0.f;

    bf16x8 bfr[8];
#pragma unroll
    for (int kc = 0; kc < 8; ++kc)
        bfr[kc] = *(const bf16x8*)&Wt[(size_t)ncol * 256 + kc * 32 + lq * 8];
    float bc = b_conv[ncol];
    int g_base = gid[n0];

    float cs = 0.f, cq = 0.f;

    for (int t = 0; t < 4; ++t) {
        int bn0 = n0 + t * 64;
        __syncthreads();
#pragma unroll
        for (int i = 0; i < 2; ++i) {
            int idx = i * 1024 + tid;
            int r = idx >> 5;
            int c = idx & 31;
            int node = bn0 + r;
            ushort8 v = {0, 0, 0, 0, 0, 0, 0, 0};
            if (node < N_NODES) {
                v = (c < 16) ? *(const ushort8*)&fb[(size_t)node * IN_DIM + c * 8]
                             : *(const ushort8*)&hb[(size_t)node * IN_DIM + (c - 16) * 8];
            }
            *(ushort8*)&A_l[r * 264 + c * 8] = v;
        }
        __syncthreads();

        f32x4 acc[4];
#pragma unroll
        for (int rf = 0; rf < 4; ++rf) acc[rf] = (f32x4)0.f;
#pragma unroll
        for (int kc = 0; kc < 8; ++kc) {
#pragma unroll
            for (int rf = 0; rf < 4; ++rf) {
                bf16x8 a = *(const bf16x8*)&A_l[(rf * 16 + lr15) * 264 + kc * 32 + lq * 8];
                acc[rf] = __builtin_amdgcn_mfma_f32_16x16x32_bf16(a, bfr[kc], acc[rf], 0, 0, 0);
            }
        }

        float ps = 0.f;
        int cg = -1;
#pragma unroll
        for (int rf = 0; rf < 4; ++rf) {
#pragma unroll
            for (int j = 0; j < 4; ++j) {
                int lr = rf * 16 + lq * 4 + j;
                int node = bn0 + lr;
                if (node < N_NODES) {
                    int g = gid_s[t * 64 + lr];
                    if (g != cg) {
                        if (cg >= 0 && ps != 0.f) {
                            int slot = cg - g_base;
                            if (slot < 8) atomicAdd(&pool_l[slot][ncol], ps);
                            else          atomicAdd(&pooled_raw[cg * HID + ncol], ps);
                        }
                        ps = 0.f; cg = g;
                    }
                    float v = fmaxf(acc[rf][j] + bc, 0.f);
                    cs += v; cq += v * v; ps += v;
                }
            }
        }
        if (cg >= 0 && ps != 0.f) {
            int slot = cg - g_base;
            if (slot < 8) atomicAdd(&pool_l[slot][ncol], ps);
            else          atomicAdd(&pooled_raw[cg * HID + ncol], ps);
        }
    }

    atomicAdd(&csum_l[ncol], cs);
    atomicAdd(&csq_l[ncol], cq);
    __syncthreads();
    if (tid < 256) {
        atomicAdd(&colsum[tid], csum_l[tid]);
        atomicAdd(&colsq[tid], csq_l[tid]);
    }
#pragma unroll
    for (int i = 0; i < 2; ++i) {
        int idx = i * 1024 + tid;
        int slot = idx >> 8, c = idx & 255;
        int gg = g_base + slot;
        float v = pool_l[slot][c];
        if (gg < NG && v != 0.f) atomicAdd(&pooled_raw[gg * HID + c], v);
    }
}

// -------- lp1: fused conv-BN finalize + linear + relu + BN stats --------
__global__ __launch_bounds__(256) void k_lp1(const float* __restrict__ colsum,
                                             const float* __restrict__ colsq,
                                             const float* __restrict__ gamma_c,
                                             const float* __restrict__ beta_c,
                                             const int* __restrict__ start,
                                             const float* __restrict__ pooled_raw,
                                             const float* __restrict__ W,
                                             const float* __restrict__ b,
                                             float* __restrict__ yrelu,
                                             float* __restrict__ csum,
                                             float* __restrict__ csq) {
    __shared__ float xl[256];
    int g = blockIdx.x, c = threadIdx.x;
    float mu = colsum[c] * (1.0f / N_NODES);
    float var = colsq[c] * (1.0f / N_NODES) - mu * mu;
    float a = gamma_c[c] * rsqrtf(var + EPSV);
    float off = beta_c[c] - a * mu;
    float cg = (float)(start[g + 1] - start[g]);
    xl[c] = a * pooled_raw[g * HID + c] + cg * off;
    __syncthreads();
    float acc = b[c];
#pragma unroll 8
    for (int k = 0; k < HID; ++k) acc = fmaf(xl[k], W[k * HID + c], acc);
    float r = fmaxf(acc, 0.f);
    yrelu[g * HID + c] = r;
    atomicAdd(&csum[c], r);
    atomicAdd(&csq[c], r * r);
}

// -------- lp linear: y = relu(x@W + b), accumulate BN stats --------
__global__ __launch_bounds__(256) void k_lp(const float* __restrict__ x,
                                            const float* __restrict__ W,
                                            const float* __restrict__ b,
                                            float* __restrict__ yrelu,
                                            float* __restrict__ csum,
                                            float* __restrict__ csq) {
    __shared__ float xl[256];
    int g = blockIdx.x, c = threadIdx.x;
    xl[c] = x[g * HID + c];
    __syncthreads();
    float acc = b[c];
#pragma unroll 8
    for (int k = 0; k < HID; ++k) acc = fmaf(xl[k], W[k * HID + c], acc);
    float r = fmaxf(acc, 0.f);
    yrelu[g * HID + c] = r;
    atomicAdd(&csum[c], r);
    atomicAdd(&csq[c], r * r);
}

// -------- apply BN (write p to ws and d_out) --------
__global__ void k_bn(const float* __restrict__ yrelu, const float* __restrict__ csum,
                     const float* __restrict__ csq, const float* __restrict__ gamma,
                     const float* __restrict__ beta, float* __restrict__ out_a,
                     float* __restrict__ out_b) {
    int g = blockIdx.x, c = threadIdx.x;
    float mu = csum[c] * (1.f / NG);
    float var = csq[c] * (1.f / NG) - mu * mu;
    float a = gamma[c] * rsqrtf(var + EPSV);
    float v = (yrelu[g * HID + c] - mu) * a + beta[c];
    out_a[g * HID + c] = v;
    out_b[g * HID + c] = v;
}

// -------- apply BN + log_softmax --------
__global__ __launch_bounds__(256) void k_bnsm(const float* __restrict__ yrelu,
                                              const float* __restrict__ csum,
                                              const float* __restrict__ csq,
                                              const float* __restrict__ gamma,
                                              const float* __restrict__ beta,
                                              float* __restrict__ out) {
    __shared__ float red[256];
    int g = blockIdx.x, c = threadIdx.x;
    float mu = csum[c] * (1.f / NG);
    float var = csq[c] * (1.f / NG) - mu * mu;
    float a = gamma[c] * rsqrtf(var + EPSV);
    float z = (yrelu[g * HID + c] - mu) * a + beta[c];
    red[c] = z;
    __syncthreads();
    for (int s = 128; s > 0; s >>= 1) {
        if (c < s) red[c] = fmaxf(red[c], red[c + s]);
        __syncthreads();
    }
    float m = red[0];
    __syncthreads();
    red[c] = expf(z - m);
    __syncthreads();
    for (int s = 128; s > 0; s >>= 1) {
        if (c < s) red[c] += red[c + s];
        __syncthreads();
    }
    float lse = m + logf(red[0]);
    out[g * HID + c] = z - lse;
}

extern "C" void kernel_launch(void* const* d_in, const int* in_sizes, int n_in,
                              void* d_out, int out_size, void* d_ws, size_t ws_size,
                              hipStream_t stream) {
    const float* feat    = (const float*)d_in[0];
    const float* W_self  = (const float*)d_in[1];
    const float* W_neigh = (const float*)d_in[2];
    const float* b_conv  = (const float*)d_in[3];
    const float* g_conv  = (const float*)d_in[4];
    const float* be_conv = (const float*)d_in[5];
    const float* W_lp    = (const float*)d_in[6];
    const float* b_lp    = (const float*)d_in[7];
    const float* g_lp    = (const float*)d_in[8];
    const float* be_lp   = (const float*)d_in[9];
    const int* src = (const int*)d_in[10];
    const int* dst = (const int*)d_in[11];
    const int* gid = (const int*)d_in[12];

    char* ws = (char*)d_ws;
    unsigned short* Wt = (unsigned short*)(ws + OFF_WT);
    int*   start      = (int*)(ws + OFF_START);
    float* colsum     = (float*)(ws + OFF_CSUM);
    float* colsq      = (float*)(ws + OFF_CSQ);
    float* pooled_raw = (float*)(ws + OFF_POOLR);
    float* csum1      = (float*)(ws + OFF_CSUM1);
    float* csq1       = (float*)(ws + OFF_CSQ1);
    float* csum2      = (float*)(ws + OFF_CSUM2);
    float* csq2       = (float*)(ws + OFF_CSQ2);
    int*   bbase      = (int*)(ws + OFF_BBASE);
    int*   histm      = (int*)(ws + OFF_HISTM);
    int*   bases      = (int*)(ws + OFF_BASES);
    int*   row_off    = (int*)(ws + OFF_ROWOFF);
    float* y1r        = (float*)(ws + OFF_Y1R);
    float* p_buf      = (float*)(ws + OFF_PBUF);
    float* y2r        = (float*)(ws + OFF_Y2R);
    int*   sorted_src = (int*)(ws + OFF_SSRC);
    unsigned short* fb = (unsigned short*)(ws + OFF_FB16);
    unsigned short* hb = (unsigned short*)(ws + OFF_HN16);
    int*   bsrc       = (int*)(ws + OFF_BSRC);              // aliases hb
    unsigned char* bdlo = (unsigned char*)(ws + OFF_BDLO);  // aliases hb

    float* out_ls = (float*)d_out;             // [64,256] log_softmax
    float* out_p  = out_ls + NG * HID;         // [64,256] p

    hipMemsetAsync(ws + ZERO_START, 0, ZERO_END - ZERO_START, stream);
    k_prep<<<2048, 256, 0, stream>>>(feat, gid, W_self, W_neigh, fb, start, Wt);
    k_hist<<<HBLK, 1024, 0, stream>>>(dst, histm);
    k_bscan<<<1, 512, 0, stream>>>(histm, bbase, bases);
    k_bucket<<<HBLK, 1024, 0, stream>>>(src, dst, bases, bsrc, bdlo);
    k_lsort<<<NBLK, 256, 0, stream>>>(bbase, bsrc, bdlo, sorted_src, row_off);
    k_agg<<<25000, 256, 0, stream>>>(fb, row_off, sorted_src, hb);
    k_gemm<<<NBLK, 1024, 0, stream>>>(fb, hb, Wt, b_conv, gid, colsum, colsq, pooled_raw);
    k_lp1<<<NG, 256, 0, stream>>>(colsum, colsq, g_conv, be_conv, start, pooled_raw,
                                  W_lp, b_lp, y1r, csum1, csq1);
    k_bn<<<NG, 256, 0, stream>>>(y1r, csum1, csq1, g_lp, be_lp, p_buf, out_p);
    k_lp<<<NG, 256, 0, stream>>>(p_buf, W_lp, b_lp, y2r, csum2, csq2);
    k_bnsm<<<NG, 256, 0, stream>>>(y2r, csum2, csq2, g_lp, be_lp, out_ls);
}

// Round 7
// 301.471 us; speedup vs baseline: 1.1944x; 1.0122x over previous
//
#include <hip/hip_runtime.h>
#include <cstdint>
#include <cstddef>

#define N_NODES 100000
#define E_EDGES 1000000
#define IN_DIM  128
#define HID     256
#define NG      64
#define EPSV    1e-5f
#define NBLK    391        // ceil(N/256) = #buckets (bucket = dst>>8)
#define HBLK    64         // histogram/bucket blocks
#define EPB     15625      // edges per hist/bucket block (64*15625 = 1M)

typedef float f32x4 __attribute__((ext_vector_type(4)));
typedef __bf16 bf16x8 __attribute__((ext_vector_type(8)));
typedef unsigned short ushort8 __attribute__((ext_vector_type(8)));

// ---------------- ws layout (bytes) ----------------
static constexpr size_t OFF_WT     = 0;          // 256*256 bf16 = 131072
static constexpr size_t OFF_START  = 131072;     // 65 int
// zeroed region
static constexpr size_t ZERO_START = 131584;
static constexpr size_t OFF_CSUM   = 131584;     // 256 f32
static constexpr size_t OFF_CSQ    = 132608;     // 256 f32
static constexpr size_t OFF_POOLR  = 133632;     // 64*256 f32 -> 199168
static constexpr size_t OFF_CSUM1  = 199168;
static constexpr size_t OFF_CSQ1   = 200192;
static constexpr size_t OFF_CSUM2  = 201216;
static constexpr size_t OFF_CSQ2   = 202240;
static constexpr size_t ZERO_END   = 203264;
// non-zeroed
static constexpr size_t OFF_BBASE  = 203264;     // 392 int
static constexpr size_t OFF_HISTM  = 204832;     // 64*391 int
static constexpr size_t OFF_BASES  = 304928;     // 64*391 int
static constexpr size_t OFF_ROWOFF = 405024;     // (N+1) int -> 805028
static constexpr size_t OFF_Y1R    = 805056;     // 64*256 f32
static constexpr size_t OFF_PBUF   = 870592;     // 64*256 f32
static constexpr size_t OFF_Y2R    = 936128;     // 64*256 f32
static constexpr size_t OFF_SSRC   = 1001664;    // E int -> 5001664
static constexpr size_t OFF_FB16   = 5001664;    // N*128 bf16 -> 30601664
static constexpr size_t OFF_HN16   = 30601664;   // N*128 bf16 -> 56201664
// bucketed staging aliases HN16 (dead until k_agg writes hb)
static constexpr size_t OFF_BSRC   = 30601664;   // E int -> 34601664
static constexpr size_t OFF_BDLO   = 34601664;   // E u8  -> 35601664

__device__ __forceinline__ unsigned short f2bf(float f) {
    union { float f; unsigned u; } x; x.f = f;
    unsigned r = x.u + 0x7FFFu + ((x.u >> 16) & 1u);
    return (unsigned short)(r >> 16);
}
__device__ __forceinline__ float bf2f(unsigned short h) {
    union { unsigned u; float f; } x; x.u = ((unsigned)h) << 16;
    return x.f;
}

// -------- fused: feat->bf16 cvt + graph bounds + weight prepack --------
__global__ __launch_bounds__(256) void k_prep(const float* __restrict__ feat,
                                              const int* __restrict__ gid,
                                              const float* __restrict__ W_self,
                                              const float* __restrict__ W_neigh,
                                              unsigned short* __restrict__ fb,
                                              int* __restrict__ start,
                                              unsigned short* __restrict__ Wt) {
    int g = blockIdx.x * blockDim.x + threadIdx.x;
    int stride = gridDim.x * blockDim.x;
    const float4* f4 = (const float4*)feat;
    for (int i = g; i < (N_NODES * IN_DIM / 8); i += stride) {
        float4 a = f4[i * 2], b = f4[i * 2 + 1];
        ushort8 v;
        v[0] = f2bf(a.x); v[1] = f2bf(a.y); v[2] = f2bf(a.z); v[3] = f2bf(a.w);
        v[4] = f2bf(b.x); v[5] = f2bf(b.y); v[6] = f2bf(b.z); v[7] = f2bf(b.w);
        *(ushort8*)&fb[(size_t)i * 8] = v;
    }
    // weight prepack Wt[n][k]
    for (int i = g; i < HID * HID; i += stride) {
        int n = i >> 8, k = i & 255;
        float w = (k < 128) ? W_self[k * HID + n] : W_neigh[(k - 128) * HID + n];
        Wt[i] = f2bf(w);
    }
    // graph segment boundaries (gid sorted)
    for (int n = g; n < N_NODES; n += stride) {
        int b = gid[n];
        if (n == 0) {
            for (int q = 0; q <= b; ++q) start[q] = 0;
        } else {
            int a = gid[n - 1];
            for (int q = a + 1; q <= b; ++q) start[q] = n;
        }
        if (n == N_NODES - 1) {
            for (int q = b + 1; q <= NG; ++q) start[q] = N_NODES;
        }
    }
}

// -------- pass 1: per-block coarse histogram (LDS only, no global atomics) --------
__global__ __launch_bounds__(1024) void k_hist(const int* __restrict__ dst,
                                               int* __restrict__ histm) {
    __shared__ int h[NBLK];
    int blk = blockIdx.x, t = threadIdx.x;
    for (int i = t; i < NBLK; i += 1024) h[i] = 0;
    __syncthreads();
    int e0 = blk * EPB, e1 = e0 + EPB;
    for (int e = e0 + t; e < e1; e += 1024) atomicAdd(&h[dst[e] >> 8], 1);
    __syncthreads();
    for (int i = t; i < NBLK; i += 1024) histm[blk * NBLK + i] = h[i];
}

// -------- pass 2: bucket totals, exclusive scan, per-block bases --------
__global__ __launch_bounds__(512) void k_bscan(const int* __restrict__ histm,
                                               int* __restrict__ bbase,
                                               int* __restrict__ bases) {
    __shared__ int tot[512];
    int t = threadIdx.x;
    int s = 0;
    if (t < NBLK)
        for (int blk = 0; blk < HBLK; ++blk) s += histm[blk * NBLK + t];
    tot[t] = (t < NBLK) ? s : 0;
    __syncthreads();
    for (int off = 1; off < 512; off <<= 1) {
        int add = (t >= off) ? tot[t - off] : 0;
        __syncthreads();
        tot[t] += add;
        __syncthreads();
    }
    if (t < NBLK) {
        int excl = tot[t] - s;      // exclusive prefix (tot is inclusive)
        bbase[t] = excl;
        int run = excl;
        for (int blk = 0; blk < HBLK; ++blk) {
            bases[blk * NBLK + t] = run;
            run += histm[blk * NBLK + t];
        }
    }
    if (t == 0) bbase[NBLK] = E_EDGES;
}

// -------- pass 3: bucketed scatter (LDS cursors, grouped writes) --------
__global__ __launch_bounds__(1024) void k_bucket(const int* __restrict__ src,
                                                 const int* __restrict__ dst,
                                                 const int* __restrict__ bases,
                                                 int* __restrict__ bsrc,
                                                 unsigned char* __restrict__ bdlo) {
    __shared__ int cur[NBLK];
    int blk = blockIdx.x, t = threadIdx.x;
    for (int i = t; i < NBLK; i += 1024) cur[i] = bases[blk * NBLK + i];
    __syncthreads();
    int e0 = blk * EPB, e1 = e0 + EPB;
    for (int e = e0 + t; e < e1; e += 1024) {
        int d = dst[e];
        int pos = atomicAdd(&cur[d >> 8], 1);
        bsrc[pos] = src[e];
        bdlo[pos] = (unsigned char)(d & 255);
    }
}

// -------- pass 4: per-bucket local counting sort -> sorted_src + row_off --------
__global__ __launch_bounds__(256) void k_lsort(const int* __restrict__ bbase,
                                               const int* __restrict__ bsrc,
                                               const unsigned char* __restrict__ bdlo,
                                               int* __restrict__ sorted_src,
                                               int* __restrict__ row_off) {
    __shared__ int h[256];
    __shared__ int cur[256];
    int b = blockIdx.x, t = threadIdx.x;
    int base = bbase[b], end = bbase[b + 1];
    h[t] = 0;
    __syncthreads();
    for (int e = base + t; e < end; e += 256) atomicAdd(&h[bdlo[e]], 1);
    __syncthreads();
    int v = h[t];
    for (int off = 1; off < 256; off <<= 1) {
        int add = (t >= off) ? h[t - off] : 0;
        __syncthreads();
        h[t] += add;
        __syncthreads();
    }
    int excl = h[t] - v;
    int node = b * 256 + t;
    if (node < N_NODES) row_off[node] = base + excl;
    cur[t] = excl;
    __syncthreads();
    for (int e = base + t; e < end; e += 256) {
        int d = bdlo[e];
        int pos = base + atomicAdd(&cur[d], 1);
        sorted_src[pos] = bsrc[e];
    }
    if (b == 0 && t == 0) row_off[N_NODES] = E_EDGES;
}

// -------- mean aggregation (bf16 gather, bf16 out): one wave per node --------
__global__ __launch_bounds__(256) void k_agg(const unsigned short* __restrict__ fb,
                                             const int* __restrict__ row_off,
                                             const int* __restrict__ sorted_src,
                                             unsigned short* __restrict__ hb) {
    int wave = threadIdx.x >> 6;
    int lane = threadIdx.x & 63;
    int n = blockIdx.x * 4 + wave;
    if (n >= N_NODES) return;
    int k0 = __builtin_amdgcn_readfirstlane(row_off[n]);
    int k1 = __builtin_amdgcn_readfirstlane(row_off[n + 1]);
    float ax = 0.f, ay = 0.f;
    int k = k0;
    for (; k + 8 <= k1; k += 8) {
        int s[8];
#pragma unroll
        for (int q = 0; q < 8; ++q) s[q] = sorted_src[k + q];
        unsigned u[8];
#pragma unroll
        for (int q = 0; q < 8; ++q) u[q] = *(const unsigned*)&fb[(size_t)s[q] * IN_DIM + lane * 2];
#pragma unroll
        for (int q = 0; q < 8; ++q) { ax += bf2f(u[q] & 0xffff); ay += bf2f(u[q] >> 16); }
    }
    if (k + 4 <= k1) {
        int s[4];
#pragma unroll
        for (int q = 0; q < 4; ++q) s[q] = sorted_src[k + q];
        unsigned u[4];
#pragma unroll
        for (int q = 0; q < 4; ++q) u[q] = *(const unsigned*)&fb[(size_t)s[q] * IN_DIM + lane * 2];
#pragma unroll
        for (int q = 0; q < 4; ++q) { ax += bf2f(u[q] & 0xffff); ay += bf2f(u[q] >> 16); }
        k += 4;
    }
    for (; k < k1; ++k) {
        unsigned u0 = *(const unsigned*)&fb[(size_t)sorted_src[k] * IN_DIM + lane * 2];
        ax += bf2f(u0 & 0xffff);
        ay += bf2f(u0 >> 16);
    }
    float inv = 1.f / fmaxf((float)(k1 - k0), 1.f);
    unsigned out = (unsigned)f2bf(ax * inv) | ((unsigned)f2bf(ay * inv) << 16);
    *(unsigned*)&hb[(size_t)n * IN_DIM + lane * 2] = out;
}

// -------- MFMA conv GEMM + relu + BN stats + graph pooling --------
// 16 waves; wave w owns cols [w*16,w*16+16), B in VGPRs. 256 rows/block, 4 tiles of 64,
// register-prefetched staging (loads for tile t+1 in flight during tile t's MFMA).
__global__ __launch_bounds__(1024, 4) void k_gemm(const unsigned short* __restrict__ fb,
                                                  const unsigned short* __restrict__ hb,
                                                  const unsigned short* __restrict__ Wt,
                                                  const float* __restrict__ b_conv,
                                                  const int* __restrict__ gid,
                                                  float* __restrict__ colsum,
                                                  float* __restrict__ colsq,
                                                  float* __restrict__ pooled_raw) {
    __shared__ unsigned short A_l[64 * 264];   // 64 rows x 256 k, stride 264 (pad 8)
    __shared__ float pool_l[8][256];
    __shared__ float csum_l[256], csq_l[256];
    __shared__ int gid_s[256];

    int tid = threadIdx.x;
    int lane = tid & 63;
    int wid = tid >> 6;            // 0..15
    int lr15 = lane & 15;
    int lq = lane >> 4;            // 0..3
    int ncol = wid * 16 + lr15;
    int n0 = blockIdx.x * 256;

    if (tid < 256) {
        csum_l[tid] = 0.f; csq_l[tid] = 0.f;
        gid_s[tid] = (n0 + tid < N_NODES) ? gid[n0 + tid] : 0x7fffffff;
    }
    ((float*)pool_l)[tid] = 0.f;
    ((float*)pool_l)[1024 + tid] = 0.f;

    bf16x8 bfr[8];
#pragma unroll
    for (int kc = 0; kc < 8; ++kc)
        bfr[kc] = *(const bf16x8*)&Wt[(size_t)ncol * 256 + kc * 32 + lq * 8];
    float bc = b_conv[ncol];
    int g_base = gid[n0];

    float cs = 0.f, cq = 0.f;

    // per-thread staging coords (2 chunks of 16B)
    int r0 = tid >> 5,            c0 = tid & 31;
    int r1 = (1024 + tid) >> 5,   c1 = tid & 31;

    // prefetch tile 0 into registers
    ushort8 pfa = {0,0,0,0,0,0,0,0}, pfb = {0,0,0,0,0,0,0,0};
    {
        int nodea = n0 + r0, nodeb = n0 + r1;
        if (nodea < N_NODES)
            pfa = (c0 < 16) ? *(const ushort8*)&fb[(size_t)nodea * IN_DIM + c0 * 8]
                            : *(const ushort8*)&hb[(size_t)nodea * IN_DIM + (c0 - 16) * 8];
        if (nodeb < N_NODES)
            pfb = (c1 < 16) ? *(const ushort8*)&fb[(size_t)nodeb * IN_DIM + c1 * 8]
                            : *(const ushort8*)&hb[(size_t)nodeb * IN_DIM + (c1 - 16) * 8];
    }

    for (int t = 0; t < 4; ++t) {
        int bn0 = n0 + t * 64;
        __syncthreads();   // A_l free (previous tile's reads done) / init done
        // write prefetched tile into LDS
        *(ushort8*)&A_l[r0 * 264 + c0 * 8] = pfa;
        *(ushort8*)&A_l[r1 * 264 + c1 * 8] = pfb;
        // issue next tile's loads; they stay in flight through this tile's MFMA
        if (t < 3) {
            int nb = bn0 + 64;
            int nodea = nb + r0, nodeb = nb + r1;
            ushort8 va = {0,0,0,0,0,0,0,0}, vb = {0,0,0,0,0,0,0,0};
            if (nodea < N_NODES)
                va = (c0 < 16) ? *(const ushort8*)&fb[(size_t)nodea * IN_DIM + c0 * 8]
                               : *(const ushort8*)&hb[(size_t)nodea * IN_DIM + (c0 - 16) * 8];
            if (nodeb < N_NODES)
                vb = (c1 < 16) ? *(const ushort8*)&fb[(size_t)nodeb * IN_DIM + c1 * 8]
                               : *(const ushort8*)&hb[(size_t)nodeb * IN_DIM + (c1 - 16) * 8];
            pfa = va; pfb = vb;
        }
        __syncthreads();   // A_l ready

        f32x4 acc[4];
#pragma unroll
        for (int rf = 0; rf < 4; ++rf) acc[rf] = (f32x4)0.f;
#pragma unroll
        for (int kc = 0; kc < 8; ++kc) {
#pragma unroll
            for (int rf = 0; rf < 4; ++rf) {
                bf16x8 a = *(const bf16x8*)&A_l[(rf * 16 + lr15) * 264 + kc * 32 + lq * 8];
                acc[rf] = __builtin_amdgcn_mfma_f32_16x16x32_bf16(a, bfr[kc], acc[rf], 0, 0, 0);
            }
        }

        float ps = 0.f;
        int cg = -1;
#pragma unroll
        for (int rf = 0; rf < 4; ++rf) {
#pragma unroll
            for (int j = 0; j < 4; ++j) {
                int lr = rf * 16 + lq * 4 + j;
                int node = bn0 + lr;
                if (node < N_NODES) {
                    int g = gid_s[t * 64 + lr];
                    if (g != cg) {
                        if (cg >= 0 && ps != 0.f) {
                            int slot = cg - g_base;
                            if (slot < 8) atomicAdd(&pool_l[slot][ncol], ps);
                            else          atomicAdd(&pooled_raw[cg * HID + ncol], ps);
                        }
                        ps = 0.f; cg = g;
                    }
                    float v = fmaxf(acc[rf][j] + bc, 0.f);
                    cs += v; cq += v * v; ps += v;
                }
            }
        }
        if (cg >= 0 && ps != 0.f) {
            int slot = cg - g_base;
            if (slot < 8) atomicAdd(&pool_l[slot][ncol], ps);
            else          atomicAdd(&pooled_raw[cg * HID + ncol], ps);
        }
    }

    atomicAdd(&csum_l[ncol], cs);
    atomicAdd(&csq_l[ncol], cq);
    __syncthreads();
    if (tid < 256) {
        atomicAdd(&colsum[tid], csum_l[tid]);
        atomicAdd(&colsq[tid], csq_l[tid]);
    }
#pragma unroll
    for (int i = 0; i < 2; ++i) {
        int idx = i * 1024 + tid;
        int slot = idx >> 8, c = idx & 255;
        int gg = g_base + slot;
        float v = pool_l[slot][c];
        if (gg < NG && v != 0.f) atomicAdd(&pooled_raw[gg * HID + c], v);
    }
}

// -------- lp1: fused conv-BN finalize + linear + relu + BN stats --------
__global__ __launch_bounds__(256) void k_lp1(const float* __restrict__ colsum,
                                             const float* __restrict__ colsq,
                                             const float* __restrict__ gamma_c,
                                             const float* __restrict__ beta_c,
                                             const int* __restrict__ start,
                                             const float* __restrict__ pooled_raw,
                                             const float* __restrict__ W,
                                             const float* __restrict__ b,
                                             float* __restrict__ yrelu,
                                             float* __restrict__ csum,
                                             float* __restrict__ csq) {
    __shared__ float xl[256];
    int g = blockIdx.x, c = threadIdx.x;
    float mu = colsum[c] * (1.0f / N_NODES);
    float var = colsq[c] * (1.0f / N_NODES) - mu * mu;
    float a = gamma_c[c] * rsqrtf(var + EPSV);
    float off = beta_c[c] - a * mu;
    float cg = (float)(start[g + 1] - start[g]);
    xl[c] = a * pooled_raw[g * HID + c] + cg * off;
    __syncthreads();
    float acc = b[c];
#pragma unroll 8
    for (int k = 0; k < HID; ++k) acc = fmaf(xl[k], W[k * HID + c], acc);
    float r = fmaxf(acc, 0.f);
    yrelu[g * HID + c] = r;
    atomicAdd(&csum[c], r);
    atomicAdd(&csq[c], r * r);
}

// -------- lp linear: y = relu(x@W + b), accumulate BN stats --------
__global__ __launch_bounds__(256) void k_lp(const float* __restrict__ x,
                                            const float* __restrict__ W,
                                            const float* __restrict__ b,
                                            float* __restrict__ yrelu,
                                            float* __restrict__ csum,
                                            float* __restrict__ csq) {
    __shared__ float xl[256];
    int g = blockIdx.x, c = threadIdx.x;
    xl[c] = x[g * HID + c];
    __syncthreads();
    float acc = b[c];
#pragma unroll 8
    for (int k = 0; k < HID; ++k) acc = fmaf(xl[k], W[k * HID + c], acc);
    float r = fmaxf(acc, 0.f);
    yrelu[g * HID + c] = r;
    atomicAdd(&csum[c], r);
    atomicAdd(&csq[c], r * r);
}

// -------- apply BN (write p to ws and d_out) --------
__global__ void k_bn(const float* __restrict__ yrelu, const float* __restrict__ csum,
                     const float* __restrict__ csq, const float* __restrict__ gamma,
                     const float* __restrict__ beta, float* __restrict__ out_a,
                     float* __restrict__ out_b) {
    int g = blockIdx.x, c = threadIdx.x;
    float mu = csum[c] * (1.f / NG);
    float var = csq[c] * (1.f / NG) - mu * mu;
    float a = gamma[c] * rsqrtf(var + EPSV);
    float v = (yrelu[g * HID + c] - mu) * a + beta[c];
    out_a[g * HID + c] = v;
    out_b[g * HID + c] = v;
}

// -------- apply BN + log_softmax --------
__global__ __launch_bounds__(256) void k_bnsm(const float* __restrict__ yrelu,
                                              const float* __restrict__ csum,
                                              const float* __restrict__ csq,
                                              const float* __restrict__ gamma,
                                              const float* __restrict__ beta,
                                              float* __restrict__ out) {
    __shared__ float red[256];
    int g = blockIdx.x, c = threadIdx.x;
    float mu = csum[c] * (1.f / NG);
    float var = csq[c] * (1.f / NG) - mu * mu;
    float a = gamma[c] * rsqrtf(var + EPSV);
    float z = (yrelu[g * HID + c] - mu) * a + beta[c];
    red[c] = z;
    __syncthreads();
    for (int s = 128; s > 0; s >>= 1) {
        if (c < s) red[c] = fmaxf(red[c], red[c + s]);
        __syncthreads();
    }
    float m = red[0];
    __syncthreads();
    red[c] = expf(z - m);
    __syncthreads();
    for (int s = 128; s > 0; s >>= 1) {
        if (c < s) red[c] += red[c + s];
        __syncthreads();
    }
    float lse = m + logf(red[0]);
    out[g * HID + c] = z - lse;
}

extern "C" void kernel_launch(void* const* d_in, const int* in_sizes, int n_in,
                              void* d_out, int out_size, void* d_ws, size_t ws_size,
                              hipStream_t stream) {
    const float* feat    = (const float*)d_in[0];
    const float* W_self  = (const float*)d_in[1];
    const float* W_neigh = (const float*)d_in[2];
    const float* b_conv  = (const float*)d_in[3];
    const float* g_conv  = (const float*)d_in[4];
    const float* be_conv = (const float*)d_in[5];
    const float* W_lp    = (const float*)d_in[6];
    const float* b_lp    = (const float*)d_in[7];
    const float* g_lp    = (const float*)d_in[8];
    const float* be_lp   = (const float*)d_in[9];
    const int* src = (const int*)d_in[10];
    const int* dst = (const int*)d_in[11];
    const int* gid = (const int*)d_in[12];

    char* ws = (char*)d_ws;
    unsigned short* Wt = (unsigned short*)(ws + OFF_WT);
    int*   start      = (int*)(ws + OFF_START);
    float* colsum     = (float*)(ws + OFF_CSUM);
    float* colsq      = (float*)(ws + OFF_CSQ);
    float* pooled_raw = (float*)(ws + OFF_POOLR);
    float* csum1      = (float*)(ws + OFF_CSUM1);
    float* csq1       = (float*)(ws + OFF_CSQ1);
    float* csum2      = (float*)(ws + OFF_CSUM2);
    float* csq2       = (float*)(ws + OFF_CSQ2);
    int*   bbase      = (int*)(ws + OFF_BBASE);
    int*   histm      = (int*)(ws + OFF_HISTM);
    int*   bases      = (int*)(ws + OFF_BASES);
    int*   row_off    = (int*)(ws + OFF_ROWOFF);
    float* y1r        = (float*)(ws + OFF_Y1R);
    float* p_buf      = (float*)(ws + OFF_PBUF);
    float* y2r        = (float*)(ws + OFF_Y2R);
    int*   sorted_src = (int*)(ws + OFF_SSRC);
    unsigned short* fb = (unsigned short*)(ws + OFF_FB16);
    unsigned short* hb = (unsigned short*)(ws + OFF_HN16);
    int*   bsrc       = (int*)(ws + OFF_BSRC);              // aliases hb
    unsigned char* bdlo = (unsigned char*)(ws + OFF_BDLO);  // aliases hb

    float* out_ls = (float*)d_out;             // [64,256] log_softmax
    float* out_p  = out_ls + NG * HID;         // [64,256] p

    hipMemsetAsync(ws + ZERO_START, 0, ZERO_END - ZERO_START, stream);
    k_prep<<<2048, 256, 0, stream>>>(feat, gid, W_self, W_neigh, fb, start, Wt);
    k_hist<<<HBLK, 1024, 0, stream>>>(dst, histm);
    k_bscan<<<1, 512, 0, stream>>>(histm, bbase, bases);
    k_bucket<<<HBLK, 1024, 0, stream>>>(src, dst, bases, bsrc, bdlo);
    k_lsort<<<NBLK, 256, 0, stream>>>(bbase, bsrc, bdlo, sorted_src, row_off);
    k_agg<<<25000, 256, 0, stream>>>(fb, row_off, sorted_src, hb);
    k_gemm<<<NBLK, 1024, 0, stream>>>(fb, hb, Wt, b_conv, gid, colsum, colsq, pooled_raw);
    k_lp1<<<NG, 256, 0, stream>>>(colsum, colsq, g_conv, be_conv, start, pooled_raw,
                                  W_lp, b_lp, y1r, csum1, csq1);
    k_bn<<<NG, 256, 0, stream>>>(y1r, csum1, csq1, g_lp, be_lp, p_buf, out_p);
    k_lp<<<NG, 256, 0, stream>>>(p_buf, W_lp, b_lp, y2r, csum2, csq2);
    k_bnsm<<<NG, 256, 0, stream>>>(y2r, csum2, csq2, g_lp, be_lp, out_ls);
}